// Round 14
// baseline (4938.539 us; speedup 1.0000x reference)
//
#include <hip/hip_runtime.h>
#include <hip/hip_fp16.h>
#include <hip/hip_bf16.h>
#include <math.h>

#define H 128
#define SSTEPS 3
#define NE 131072
#define NT 5
#define NCELL 16384
#define NCLU 1088
#define G4 512
#define MSGW 640     // 5*H message block (fp16, column-permuted per type)
#define AKT 28       // Apack kt count (896 K-cols / 32)
#define EB 128

typedef unsigned short u16;
typedef unsigned int u32;
typedef __attribute__((ext_vector_type(8))) short short8;
typedef __attribute__((ext_vector_type(8))) unsigned short ushort8;
typedef __attribute__((ext_vector_type(4))) unsigned short ushort4v;
typedef __attribute__((ext_vector_type(4))) float f32x4;
typedef __attribute__((ext_vector_type(4))) unsigned int uint4v;

__device__ __forceinline__ u16 f2bf(float f) {
    __hip_bfloat16 h = __float2bfloat16(f);   // RNE; pairs fuse to v_cvt_pk_bf16_f32
    u16 u;
    __builtin_memcpy(&u, &h, 2);
    return u;
}
__device__ __forceinline__ float bf2f(u16 h) {
    return __uint_as_float(((unsigned int)h) << 16);
}
__device__ __forceinline__ float h2f(u16 r) {
    __half hv;
    __builtin_memcpy(&hv, &r, 2);
    return __half2float(hv);
}

// ---------------- avg of class embeddings 1..16 per batch ----------------
__global__ __launch_bounds__(128) void k_avg(const float* __restrict__ emb,
                                             float* __restrict__ avg) {
    int b = blockIdx.x, hc = threadIdx.x;
    float s = 0.f;
#pragma unroll
    for (int r = 1; r <= 16; ++r) s += emb[(b * 17 + r) * H + hc];
    avg[b * H + hc] = s * (1.0f / 16.0f);
}

// ---------------- init: cell_x -> Apack kt 0:4 (hi only); zero cst ----------------
__global__ __launch_bounds__(256) void k_init(const int* __restrict__ q,
                                              const float* __restrict__ emb,
                                              const float* __restrict__ avg,
                                              u16* __restrict__ Ap,
                                              float* __restrict__ cst) {
    __shared__ float sx[16][132];
    int mtile = blockIdx.x, tid = threadIdx.x;
#pragma unroll
    for (int e = 0; e < 8; ++e) {
        int idx = e * 256 + tid;
        int row = idx >> 7, c = idx & 127;
        int grow = mtile * 16 + row;
        int b = grow >> 8;
        int qi = q[grow];
        const float* src = (qi == 0) ? (avg + b * H) : (emb + (b * 17 + qi) * H);
        float v = src[c];
        sx[row][c] = v;
        cst[(size_t)grow * H + c] = 0.f;
    }
    __syncthreads();
    int kt = tid >> 6, lane = tid & 63;
    int row = lane & 15, c0 = kt * 32 + ((lane >> 4) << 3);
    ushort8 hh;
#pragma unroll
    for (int i = 0; i < 8; ++i) hh[i] = f2bf(sx[row][c0 + i]);
    size_t fo = ((size_t)(mtile * AKT + kt) * 64 + lane) * 8;
    *reinterpret_cast<ushort8*>(Ap + fo) = hh;
}

// ---------------- zero msg buffer (fp16, 21MB) ----------------
__global__ __launch_bounds__(256) void k_zeromsg(__half* __restrict__ msg) {
    int idx = blockIdx.x * 256 + threadIdx.x;
    reinterpret_cast<float4*>(msg)[idx] = make_float4(0.f, 0.f, 0.f, 0.f);
}

// ---------------- dst-bucket counting sort (8 buckets/type, exact) ----------------
__global__ __launch_bounds__(64) void k_bzero(u32* __restrict__ bcnt) {
    if (threadIdx.x < 40) bcnt[threadIdx.x] = 0;
}
__global__ __launch_bounds__(256) void k_bcount(const int* __restrict__ edges,
                                                u32* __restrict__ bcnt) {
    int gid = blockIdx.x * 256 + threadIdx.x;   // NT*NE
    int t = gid >> 17, e = gid & (NE - 1);
    int d = edges[(t * 2 + 1) * NE + e];
    atomicAdd(&bcnt[t * 8 + (d >> 11)], 1u);
}
__global__ __launch_bounds__(64) void k_bscan(const u32* __restrict__ bcnt,
                                              u32* __restrict__ bcur) {
    if (threadIdx.x == 0) {
        for (int t = 0; t < NT; ++t) {
            u32 run = 0;
            for (int b = 0; b < 8; ++b) {
                bcur[t * 8 + b] = run;
                run += bcnt[t * 8 + b];
            }
        }
    }
}
__global__ __launch_bounds__(256) void k_bscatter(const int* __restrict__ edges,
                                                  u32* __restrict__ bcur,
                                                  int* __restrict__ esrc,
                                                  int* __restrict__ edst) {
    int gid = blockIdx.x * 256 + threadIdx.x;   // NT*NE
    int t = gid >> 17, e = gid & (NE - 1);
    int s = edges[(t * 2) * NE + e];
    int d = edges[(t * 2 + 1) * NE + e];
    u32 slot = atomicAdd(&bcur[t * 8 + (d >> 11)], 1u);
    esrc[(size_t)t * NE + slot] = s;
    edst[(size_t)t * NE + slot] = d;
}

// ---------------- fp32 GEMM -> bf16 out (Ps0 only; tiny) ----------------
__global__ __launch_bounds__(256) void k_gemm32(const float* __restrict__ A, int lda,
                                                const float* __restrict__ B, int ldb,
                                                u16* __restrict__ C, int ldc, int K) {
    __shared__ float As[64][33];
    __shared__ float Bs[32][64];
    int tid = threadIdx.x;
    int ty = tid >> 4, tx = tid & 15;
    int rbase = blockIdx.x * 64, cbase = blockIdx.y * 64;
    float acc[4][4] = {};
    for (int k0 = 0; k0 < K; k0 += 32) {
        __syncthreads();
#pragma unroll
        for (int i = 0; i < 8; ++i) {
            int id = tid + i * 256;
            int r = id >> 5, c = id & 31;
            As[r][c] = A[(size_t)(rbase + r) * lda + k0 + c];
        }
#pragma unroll
        for (int i = 0; i < 8; ++i) {
            int id = tid + i * 256;
            int r = id >> 6, c = id & 63;
            Bs[r][c] = B[(size_t)(k0 + r) * ldb + cbase + c];
        }
        __syncthreads();
#pragma unroll 8
        for (int kk = 0; kk < 32; ++kk) {
            float a[4], bv[4];
#pragma unroll
            for (int i = 0; i < 4; ++i) a[i] = As[ty * 4 + i][kk];
#pragma unroll
            for (int j = 0; j < 4; ++j) bv[j] = Bs[kk][tx * 4 + j];
#pragma unroll
            for (int i = 0; i < 4; ++i)
#pragma unroll
                for (int j = 0; j < 4; ++j) acc[i][j] = fmaf(a[i], bv[j], acc[i][j]);
        }
    }
#pragma unroll
    for (int i = 0; i < 4; ++i)
#pragma unroll
        for (int j = 0; j < 4; ++j)
            C[(size_t)(rbase + ty * 4 + i) * ldc + cbase + tx * 4 + j] = f2bf(acc[i][j]);
}

// ---------------- W2/W3/W4 -> fragment-packed bf16 hi/lo ----------------
__global__ __launch_bounds__(256) void k_prepw(const float* __restrict__ W2,
                                               const float* __restrict__ W3,
                                               const float* __restrict__ W4,
                                               u16* __restrict__ WF) {
    int bid = blockIdx.x;                  // 240 = 5*3*2*8
    int t = bid / 48;
    int l = (bid / 16) % 3;
    int p = (bid / 8) % 2;
    int nt = bid % 8;
    int tid = threadIdx.x;
    int ks = tid >> 6, lane = tid & 63;
    const float* W = (l == 0 ? W2 : l == 1 ? W3 : W4) + t * 16384;
    int n = nt * 16 + (lane & 15);
    int kb = ks * 32 + (lane >> 4) * 8;
    ushort8 o;
#pragma unroll
    for (int i = 0; i < 8; ++i) {
        float w = W[(size_t)(kb + i) * H + n];
        u16 h = f2bf(w);
        o[i] = (p == 0) ? h : f2bf(w - bf2f(h));
    }
    size_t base = ((size_t)((((t * 3 + l) * 2 + p) * 8 + nt) * 4 + ks) * 64 + lane) * 8;
    *reinterpret_cast<ushort8*>(WF + base) = o;
}

// ---------------- pack [Wih;Whh] -> B-frags hi/lo ----------------
__global__ __launch_bounds__(256) void k_packBw(const float* __restrict__ Wih,
                                                const float* __restrict__ Whh,
                                                u16* __restrict__ Bw, size_t bplane) {
    int nt = blockIdx.x;                           // 32
    int kt = blockIdx.y * 4 + (threadIdx.x >> 6);  // grid.y=7 -> 0..27
    int lane = threadIdx.x & 63;
    int n = nt * 16 + (lane & 15);
    int k0 = kt * 32 + ((lane >> 4) << 3);
    ushort8 hh, ll;
#pragma unroll
    for (int i = 0; i < 8; ++i) {
        int k = k0 + i;
        float wv = (k < 768) ? Wih[(size_t)k * G4 + n] : Whh[(size_t)(k - 768) * G4 + n];
        u16 h = f2bf(wv);
        hh[i] = h;
        ll[i] = f2bf(wv - bf2f(h));
    }
    size_t fo = ((size_t)(nt * AKT + kt) * 64 + lane) * 8;
    *reinterpret_cast<ushort8*>(Bw + fo) = hh;
    *reinterpret_cast<ushort8*>(Bw + bplane + fo) = ll;
}

// ---------------- pack projection weights (from W1) -> B-frags hi/lo ----------------
__global__ __launch_bounds__(256) void k_packBp(const float* __restrict__ W1,
                                                u16* __restrict__ Bp, size_t bplane) {
    int nt = blockIdx.x;               // 72
    int kt = threadIdx.x >> 6;         // 0..3
    int lane = threadIdx.x & 63;
    int n = nt * 16 + (lane & 15);
    int k0 = kt * 32 + ((lane >> 4) << 3);
    int t, roff, j;
    if (n < 640) { t = n >> 7; j = n & 127; roff = 128; }
    else { int m = n - 640; t = (m >> 7) + 1; j = m & 127; roff = 0; }
    ushort8 hh, ll;
#pragma unroll
    for (int i = 0; i < 8; ++i) {
        float wv = W1[((size_t)t * 256 + roff + k0 + i) * H + j];
        u16 h = f2bf(wv);
        hh[i] = h;
        ll[i] = f2bf(wv - bf2f(h));
    }
    size_t fo = ((size_t)(nt * 4 + kt) * 64 + lane) * 8;
    *reinterpret_cast<ushort8*>(Bp + fo) = hh;
    *reinterpret_cast<ushort8*>(Bp + bplane + fo) = ll;
}

// ---------------- MFMA GEMM, 2-term (Ah*Bh + Ah*Bl); A from Ap frags, or msg fp16 for kt 4:24 ----------------
// psplit=1: bf16 out in per-type layout P9[col>>7][row][col&127]
__global__ __launch_bounds__(256) void k_gemm_bf(const u16* __restrict__ Ap,
                                                 int aktbase,
                                                 const __half* __restrict__ msgA,
                                                 const u16* __restrict__ Bp, size_t bplane,
                                                 int bKT, int nkt,
                                                 float* __restrict__ Cf, u16* __restrict__ Ch,
                                                 int ldc, int psplit) {
    int tid = threadIdx.x;
    int w = tid >> 6, lane = tid & 63;
    int wr = w >> 1, wc = w & 1;
    int mtb = blockIdx.x * 8 + wr * 4;
    int ntb = blockIdx.y * 8 + wc * 4;
    f32x4 acc[4][4] = {};
    for (int kk = 0; kk < nkt; ++kk) {
        short8 Ah[4], Bh[4], Bl[4];
        if (msgA && kk >= 4 && kk < 24) {
            // A fragment from msg fp16 (permuted type-block layout)
            int k0 = (kk - 4) * 32 + ((lane >> 4) << 3);
            int tt = k0 >> 7, fl0 = k0 & 127;
            int bit = (fl0 >> 4) & 1;
            int wbase = tt * 128 + ((fl0 >> 5) << 5) + ((fl0 & 15) << 1);  // 16-elem aligned
#pragma unroll
            for (int m = 0; m < 4; ++m) {
                int row = (mtb + m) * 16 + (lane & 15);
                const uint4v* dwp = reinterpret_cast<const uint4v*>(msgA + (size_t)row * MSGW + wbase);
                uint4v q0 = dwp[0], q1 = dwp[1];
                u32 dws[8] = {q0[0], q0[1], q0[2], q0[3], q1[0], q1[1], q1[2], q1[3]};
                short8 hv;
#pragma unroll
                for (int i = 0; i < 8; ++i) {
                    u16 raw = bit ? (u16)(dws[i] >> 16) : (u16)(dws[i] & 0xffffu);
                    hv[i] = (short)f2bf(h2f(raw));
                }
                Ah[m] = hv;
            }
        } else {
#pragma unroll
            for (int m = 0; m < 4; ++m) {
                size_t fo = ((size_t)((mtb + m) * AKT + aktbase + kk) * 64 + lane) * 8;
                Ah[m] = *reinterpret_cast<const short8*>(Ap + fo);
            }
        }
#pragma unroll
        for (int n = 0; n < 4; ++n) {
            size_t fo = ((size_t)((ntb + n) * bKT + kk) * 64 + lane) * 8;
            Bh[n] = *reinterpret_cast<const short8*>(Bp + fo);
            Bl[n] = *reinterpret_cast<const short8*>(Bp + bplane + fo);
        }
#pragma unroll
        for (int m = 0; m < 4; ++m)
#pragma unroll
            for (int n = 0; n < 4; ++n) {
                acc[m][n] = __builtin_amdgcn_mfma_f32_16x16x32_bf16(Ah[m], Bh[n], acc[m][n], 0, 0, 0);
                acc[m][n] = __builtin_amdgcn_mfma_f32_16x16x32_bf16(Ah[m], Bl[n], acc[m][n], 0, 0, 0);
            }
    }
#pragma unroll
    for (int m = 0; m < 4; ++m)
#pragma unroll
        for (int r = 0; r < 4; ++r) {
            int row = (mtb + m) * 16 + (lane >> 4) * 4 + r;
#pragma unroll
            for (int n = 0; n < 4; ++n) {
                int col = (ntb + n) * 16 + (lane & 15);
                float v = acc[m][n][r];
                if (Ch) {
                    if (psplit)
                        Ch[((size_t)(col >> 7) * NCELL + row) * H + (col & 127)] = f2bf(v);
                    else
                        Ch[(size_t)row * ldc + col] = f2bf(v);
                } else {
                    Cf[(size_t)row * ldc + col] = v;
                }
            }
        }
}

// ---------------- fused per-edge MLP; bucketed edges + XCD-affine chunks ----------------
__global__ __launch_bounds__(256, 4) void k_edge(const int* __restrict__ esrc,
                                                 const int* __restrict__ edst,
                                                 const u16* __restrict__ P,   // P9 layout
                                                 const u16* __restrict__ Ps0,
                                                 const u16* __restrict__ WF,
                                                 const float* __restrict__ bb1,
                                                 const float* __restrict__ bb2,
                                                 const float* __restrict__ bb3,
                                                 const float* __restrict__ bb4,
                                                 __half* __restrict__ msg) {
    __shared__ u16 zh[EB * H];    // 32KB, 16B-chunk XOR swizzle
    __shared__ int sdst[EB];
    int tid = threadIdx.x;
    int w = tid >> 6, lane = tid & 63;
    int bid = blockIdx.x;
    int t = bid >> 10;
    int p = bid & 1023;
    int tile = ((p & 7) << 7) | (p >> 3);   // bucket-major chunk -> XCD-affine
    int ebase = tile * EB;

    // ---- layer 1 (per-type P9 gathers; contiguous bucketed edge arrays) ----
    {
        int row = tid >> 1, half = tid & 1;
        size_t e = (size_t)t * NE + ebase + row;
        int sn = esrc[e];
        int dn = edst[e];
        if (half == 0) sdst[row] = dn;
        const u16* ps = (t == 0) ? Ps0 + (size_t)sn * H
                                 : P + ((size_t)(t + 4) * NCELL + sn) * H;
        const u16* pd = P + ((size_t)t * NCELL + dn) * H;
        const float* bb = bb1 + t * H;
#pragma unroll
        for (int cc = 0; cc < 8; ++cc) {
            int c8 = half * 8 + cc;
            ushort8 a = *reinterpret_cast<const ushort8*>(ps + c8 * 8);
            ushort8 d = *reinterpret_cast<const ushort8*>(pd + c8 * 8);
            float4 b0 = *reinterpret_cast<const float4*>(bb + c8 * 8);
            float4 b1v = *reinterpret_cast<const float4*>(bb + c8 * 8 + 4);
            float bv[8] = {b0.x, b0.y, b0.z, b0.w, b1v.x, b1v.y, b1v.z, b1v.w};
            ushort8 hh;
#pragma unroll
            for (int i = 0; i < 8; ++i)
                hh[i] = f2bf(fmaxf(bf2f(a[i]) + bf2f(d[i]) + bv[i], 0.f));
            *reinterpret_cast<ushort8*>(&zh[row * H + ((c8 ^ (row & 7)) << 3)]) = hh;
        }
    }
    __syncthreads();

    const u16* wfbase = WF + (size_t)(t * 3) * 32768;
    short8 Bh[2][4], Bl[2][4];

    // ---- layers 2,3: transposed compute mfma(W,z) -> packed b64 writeback ----
#pragma unroll 1
    for (int l = 0; l < 2; ++l) {
        const u16* wl = wfbase + l * 32768;
#pragma unroll
        for (int fg = 0; fg < 2; ++fg)
#pragma unroll
            for (int ks = 0; ks < 4; ++ks) {
                int nt = 2 * w + fg;
                Bh[fg][ks] = *reinterpret_cast<const short8*>(wl + ((nt * 4 + ks) * 64 + lane) * 8);
                Bl[fg][ks] = *reinterpret_cast<const short8*>(wl + ((32 + nt * 4 + ks) * 64 + lane) * 8);
            }
        f32x4 acc[8][2];
#pragma unroll
        for (int et = 0; et < 8; ++et)
#pragma unroll
            for (int fg = 0; fg < 2; ++fg)
                acc[et][fg] = (f32x4){0.f, 0.f, 0.f, 0.f};
#pragma unroll
        for (int et = 0; et < 8; ++et) {
            short8 Zf[4];
            int rr = et * 16 + (lane & 15);
#pragma unroll
            for (int ks = 0; ks < 4; ++ks) {
                int ch = ks * 4 + (lane >> 4);
                Zf[ks] = *reinterpret_cast<const short8*>(&zh[rr * H + ((ch ^ (rr & 7)) << 3)]);
            }
#pragma unroll
            for (int fg = 0; fg < 2; ++fg)
#pragma unroll
                for (int ks = 0; ks < 4; ++ks) {
                    acc[et][fg] = __builtin_amdgcn_mfma_f32_16x16x32_bf16(Bh[fg][ks], Zf[ks], acc[et][fg], 0, 0, 0);
                    acc[et][fg] = __builtin_amdgcn_mfma_f32_16x16x32_bf16(Bl[fg][ks], Zf[ks], acc[et][fg], 0, 0, 0);
                }
        }
        __syncthreads();   // all reads of zh done
        const float* bb = (l == 0 ? bb2 : bb3) + t * H;
        float bi[2][4];
#pragma unroll
        for (int fg = 0; fg < 2; ++fg)
#pragma unroll
            for (int r = 0; r < 4; ++r)
                bi[fg][r] = bb[(2 * w + fg) * 16 + (lane >> 4) * 4 + r];
#pragma unroll
        for (int et = 0; et < 8; ++et) {
            int e = et * 16 + (lane & 15);
#pragma unroll
            for (int fg = 0; fg < 2; ++fg) {
                int f0 = (2 * w + fg) * 16 + (lane >> 4) * 4;
                ushort4v v;
#pragma unroll
                for (int r = 0; r < 4; ++r)
                    v[r] = f2bf(fmaxf(acc[et][fg][r] + bi[fg][r], 0.f));
                int off = e * H + (((f0 >> 3) ^ (e & 7)) << 3) + (f0 & 7);
                *reinterpret_cast<ushort4v*>(&zh[off]) = v;
            }
        }
        __syncthreads();   // writes visible
    }

    // ---- layer 4: normal orientation, per-mt MFMA + packed-fp16 atomic scatter ----
    {
        const u16* wl = wfbase + 2 * 32768;
#pragma unroll
        for (int ng = 0; ng < 2; ++ng)
#pragma unroll
            for (int ks = 0; ks < 4; ++ks) {
                int nt = 2 * w + ng;
                Bh[ng][ks] = *reinterpret_cast<const short8*>(wl + ((nt * 4 + ks) * 64 + lane) * 8);
                Bl[ng][ks] = *reinterpret_cast<const short8*>(wl + ((32 + nt * 4 + ks) * 64 + lane) * 8);
            }
        const float* bb = bb4 + t * H;
        float bi[2];
#pragma unroll
        for (int ng = 0; ng < 2; ++ng) bi[ng] = bb[(2 * w + ng) * 16 + (lane & 15)];
        int pos = (w * 16 + (lane & 15)) * 2;   // even -> 4B-aligned __half2
#pragma unroll 1
        for (int mt = 0; mt < 8; ++mt) {
            short8 Ah[4];
            int rr = mt * 16 + (lane & 15);
#pragma unroll
            for (int ks = 0; ks < 4; ++ks) {
                int ch = ks * 4 + (lane >> 4);
                Ah[ks] = *reinterpret_cast<const short8*>(&zh[rr * H + ((ch ^ (rr & 7)) << 3)]);
            }
            f32x4 a0 = (f32x4){0.f, 0.f, 0.f, 0.f};
            f32x4 a1 = (f32x4){0.f, 0.f, 0.f, 0.f};
#pragma unroll
            for (int ks = 0; ks < 4; ++ks) {
                a0 = __builtin_amdgcn_mfma_f32_16x16x32_bf16(Ah[ks], Bh[0][ks], a0, 0, 0, 0);
                a0 = __builtin_amdgcn_mfma_f32_16x16x32_bf16(Ah[ks], Bl[0][ks], a0, 0, 0, 0);
                a1 = __builtin_amdgcn_mfma_f32_16x16x32_bf16(Ah[ks], Bh[1][ks], a1, 0, 0, 0);
                a1 = __builtin_amdgcn_mfma_f32_16x16x32_bf16(Ah[ks], Bl[1][ks], a1, 0, 0, 0);
            }
#pragma unroll
            for (int r = 0; r < 4; ++r) {
                int d = sdst[mt * 16 + (lane >> 4) * 4 + r];
                __half2* mp = reinterpret_cast<__half2*>(msg + (size_t)d * MSGW + t * H + pos);
                unsafeAtomicAdd(mp, __floats2half2_rn(a0[r] + bi[0], a1[r] + bi[1]));
            }
        }
    }
}

// ---------------- LSTM pointwise + h frag pack (kt 24:28, hi only) + fused logits ----------------
__global__ __launch_bounds__(256) void k_lstm(const float* __restrict__ gates,
                                              float* __restrict__ cst,
                                              u16* __restrict__ Ap,
                                              const float* __restrict__ oemb,
                                              float* __restrict__ out) {
    __shared__ float sh[16][132];
    __shared__ float oe[17][132];
    int mtile = blockIdx.x, tid = threadIdx.x;
    int b = mtile >> 4;   // 16 mtiles per batch
    for (int id = tid; id < 17 * 128; id += 256) {
        int r = id >> 7, c = id & 127;
        oe[r][c] = oemb[(b * 17 + r) * H + c];
    }
#pragma unroll
    for (int e = 0; e < 8; ++e) {
        int idx = e * 256 + tid;
        int row = idx >> 7, c = idx & 127;
        int grow = mtile * 16 + row;
        const float* g = gates + (size_t)grow * G4;
        float ig = g[c], fg = g[128 + c], gg = g[256 + c], og = g[384 + c];
        size_t ci = (size_t)grow * H + c;
        float c_old = cst[ci];
        float i_s = 1.f / (1.f + expf(-ig));
        float f_s = 1.f / (1.f + expf(-fg));
        float o_s = 1.f / (1.f + expf(-og));
        float c_new = f_s * c_old + i_s * tanhf(gg);
        float h_new = o_s * tanhf(c_new);
        cst[ci] = c_new;
        sh[row][c] = h_new;
    }
    __syncthreads();
    // h frag pack (hi only)
    {
        int kt = tid >> 6, lane = tid & 63;
        int row = lane & 15, c0 = kt * 32 + ((lane >> 4) << 3);
        ushort8 hh;
#pragma unroll
        for (int i = 0; i < 8; ++i) hh[i] = f2bf(sh[row][c0 + i]);
        size_t fo = ((size_t)(mtile * AKT + 24 + kt) * 64 + lane) * 8;
        *reinterpret_cast<ushort8*>(Ap + fo) = hh;
    }
    // logits
    {
        int row = tid & 15, cls = tid >> 4;
        const float4* hv = reinterpret_cast<const float4*>(&sh[row][0]);
        const float4* ov = reinterpret_cast<const float4*>(&oe[cls][0]);
        float a = 0.f;
#pragma unroll
        for (int v = 0; v < 32; ++v) {
            float4 h4 = hv[v], o4 = ov[v];
            a = fmaf(h4.x, o4.x, fmaf(h4.y, o4.y, fmaf(h4.z, o4.z, fmaf(h4.w, o4.w, a))));
        }
        out[(size_t)(mtile * 16 + row) * 17 + cls] = a;
        if (tid < 16) {
            const float4* hv2 = reinterpret_cast<const float4*>(&sh[tid][0]);
            const float4* ov2 = reinterpret_cast<const float4*>(&oe[16][0]);
            float a2 = 0.f;
#pragma unroll
            for (int v = 0; v < 32; ++v) {
                float4 h4 = hv2[v], o4 = ov2[v];
                a2 = fmaf(h4.x, o4.x, fmaf(h4.y, o4.y, fmaf(h4.z, o4.z, fmaf(h4.w, o4.w, a2))));
            }
            out[(size_t)(mtile * 16 + tid) * 17 + 16] = a2;
        }
    }
}

extern "C" void kernel_launch(void* const* d_in, const int* in_sizes, int n_in,
                              void* d_out, int out_size, void* d_ws, size_t ws_size,
                              hipStream_t stream) {
    (void)in_sizes; (void)n_in; (void)out_size; (void)ws_size;
    const int*   edges = (const int*)d_in[0];
    const int*   q     = (const int*)d_in[1];
    const float* emb   = (const float*)d_in[2];
    const float* oemb  = (const float*)d_in[3];
    const float* W1    = (const float*)d_in[4];
    const float* b1    = (const float*)d_in[5];
    const float* W2    = (const float*)d_in[6];
    const float* b2    = (const float*)d_in[7];
    const float* W3    = (const float*)d_in[8];
    const float* b3    = (const float*)d_in[9];
    const float* W4    = (const float*)d_in[10];
    const float* b4    = (const float*)d_in[11];
    const float* Wih   = (const float*)d_in[12];
    const float* Whh   = (const float*)d_in[13];
    float* out = (float*)d_out;

    // ---- workspace layout (bytes, 256-aligned) ----
    char* wsp = (char*)d_ws;
    size_t off = 0;
    auto alloc = [&](size_t bytes) { void* p = wsp + off; off = (off + bytes + 255) & ~(size_t)255; return p; };
    __half* msg   = (__half*)alloc((size_t)NCELL * MSGW * 2);       // 21MB fp16
    u16*   P      = (u16*)  alloc((size_t)9 * NCELL * H * 2);       // 37.7MB (P9 layout)
    float* gates  = (float*)P;                                      // alias
    float* cst    = (float*)alloc((size_t)NCELL * H * 4);
    u16*   Ps0    = (u16*)  alloc((size_t)NCLU * H * 2);
    float* avg    = (float*)alloc((size_t)64 * H * 4);
    size_t aplane = (size_t)NCELL * 896;
    u16*   Ap     = (u16*)  alloc(aplane * 2);                      // hi plane only
    u16*   WF     = (u16*)  alloc((size_t)983040 * 2);
    size_t bwpl   = (size_t)512 * 896;
    u16*   Bw     = (u16*)  alloc(bwpl * 2 * 2);
    size_t bppl   = (size_t)1152 * 128;
    u16*   Bp     = (u16*)  alloc(bppl * 2 * 2);
    int*   esrc   = (int*)  alloc((size_t)NT * NE * 4);
    int*   edst   = (int*)  alloc((size_t)NT * NE * 4);
    u32*   bcnt   = (u32*)  alloc(64 * 4);
    u32*   bcur   = (u32*)  alloc(64 * 4);

    // ---- one-time prep ----
    k_avg<<<64, 128, 0, stream>>>(emb, avg);
    k_init<<<1024, 256, 0, stream>>>(q, emb, avg, Ap, cst);
    k_prepw<<<240, 256, 0, stream>>>(W2, W3, W4, WF);
    {
        dim3 g(32, 7);
        k_packBw<<<g, 256, 0, stream>>>(Wih, Whh, Bw, bwpl);
    }
    k_packBp<<<72, 256, 0, stream>>>(W1, Bp, bppl);
    {
        dim3 g0(17, 2);
        k_gemm32<<<g0, 256, 0, stream>>>(emb, H, W1, H, Ps0, H, H);
    }
    // dst-bucket counting sort (8 buckets per type)
    k_bzero<<<1, 64, 0, stream>>>(bcnt);
    k_bcount<<<NT * NE / 256, 256, 0, stream>>>(edges, bcnt);
    k_bscan<<<1, 64, 0, stream>>>(bcnt, bcur);
    k_bscatter<<<NT * NE / 256, 256, 0, stream>>>(edges, bcur, esrc, edst);

    for (int s = 0; s < SSTEPS; ++s) {
        k_zeromsg<<<NCELL * MSGW / 8 / 256, 256, 0, stream>>>(msg);
        // P9 = h @ Wproj (bf16, per-type layout); A-frags kt 0:4 (cell_x) at s=0 else 24:28 (h)
        {
            dim3 g(128, 9);
            k_gemm_bf<<<g, 256, 0, stream>>>(Ap, (s == 0) ? 0 : 24, nullptr,
                                             Bp, bppl, 4, 4, nullptr, P, H, 1);
        }
        k_edge<<<NT * (NE / EB), 256, 0, stream>>>(esrc, edst, P, Ps0, WF,
                                                   b1, b2, b3, b4, msg);
        // gates = [cell_x, msg, h] @ [Wih; Whh]  (K = 768 at s=0, 896 else); msg read in-place
        {
            dim3 g(128, 4);
            k_gemm_bf<<<g, 256, 0, stream>>>(Ap, 0, msg, Bw, bwpl, AKT,
                                             (s == 0) ? 24 : 28, gates, nullptr, G4, 0);
        }
        k_lstm<<<1024, 256, 0, stream>>>(gates, cst, Ap, oemb,
                                         out + (size_t)s * NCELL * 17);
    }
}

// Round 15
// 1059.845 us; speedup vs baseline: 4.6597x; 4.6597x over previous
//
#include <hip/hip_runtime.h>
#include <hip/hip_fp16.h>
#include <hip/hip_bf16.h>
#include <math.h>

#define H 128
#define SSTEPS 3
#define NE 131072
#define NT 5
#define NCELL 16384
#define NCLU 1088
#define G4 512
#define MSGW 640     // 5*H message block (fp16, column-permuted per type)
#define AKT 28       // Apack kt count (896 K-cols / 32)
#define EB 128

typedef unsigned short u16;
typedef unsigned int u32;
typedef __attribute__((ext_vector_type(8))) short short8;
typedef __attribute__((ext_vector_type(8))) unsigned short ushort8;
typedef __attribute__((ext_vector_type(4))) unsigned short ushort4v;
typedef __attribute__((ext_vector_type(4))) float f32x4;
typedef __attribute__((ext_vector_type(4))) unsigned int uint4v;

__device__ __forceinline__ u16 f2bf(float f) {
    __hip_bfloat16 h = __float2bfloat16(f);   // RNE; pairs fuse to v_cvt_pk_bf16_f32
    u16 u;
    __builtin_memcpy(&u, &h, 2);
    return u;
}
__device__ __forceinline__ float bf2f(u16 h) {
    return __uint_as_float(((unsigned int)h) << 16);
}
__device__ __forceinline__ float h2f(u16 r) {
    __half hv;
    __builtin_memcpy(&hv, &r, 2);
    return __half2float(hv);
}

// ---------------- avg of class embeddings 1..16 per batch ----------------
__global__ __launch_bounds__(128) void k_avg(const float* __restrict__ emb,
                                             float* __restrict__ avg) {
    int b = blockIdx.x, hc = threadIdx.x;
    float s = 0.f;
#pragma unroll
    for (int r = 1; r <= 16; ++r) s += emb[(b * 17 + r) * H + hc];
    avg[b * H + hc] = s * (1.0f / 16.0f);
}

// ---------------- init: cell_x -> Apack kt 0:4 (hi only); zero cst ----------------
__global__ __launch_bounds__(256) void k_init(const int* __restrict__ q,
                                              const float* __restrict__ emb,
                                              const float* __restrict__ avg,
                                              u16* __restrict__ Ap,
                                              float* __restrict__ cst) {
    __shared__ float sx[16][132];
    int mtile = blockIdx.x, tid = threadIdx.x;
#pragma unroll
    for (int e = 0; e < 8; ++e) {
        int idx = e * 256 + tid;
        int row = idx >> 7, c = idx & 127;
        int grow = mtile * 16 + row;
        int b = grow >> 8;
        int qi = q[grow];
        const float* src = (qi == 0) ? (avg + b * H) : (emb + (b * 17 + qi) * H);
        float v = src[c];
        sx[row][c] = v;
        cst[(size_t)grow * H + c] = 0.f;
    }
    __syncthreads();
    int kt = tid >> 6, lane = tid & 63;
    int row = lane & 15, c0 = kt * 32 + ((lane >> 4) << 3);
    ushort8 hh;
#pragma unroll
    for (int i = 0; i < 8; ++i) hh[i] = f2bf(sx[row][c0 + i]);
    size_t fo = ((size_t)(mtile * AKT + kt) * 64 + lane) * 8;
    *reinterpret_cast<ushort8*>(Ap + fo) = hh;
}

// ---------------- zero msg buffer (fp16, 21MB) ----------------
__global__ __launch_bounds__(256) void k_zeromsg(__half* __restrict__ msg) {
    int idx = blockIdx.x * 256 + threadIdx.x;
    reinterpret_cast<float4*>(msg)[idx] = make_float4(0.f, 0.f, 0.f, 0.f);
}

// ---------------- dst-bucket counting sort (8 buckets/type) — LDS-aggregated ----------------
__global__ __launch_bounds__(64) void k_bzero(u32* __restrict__ bcnt) {
    if (threadIdx.x < 40) bcnt[threadIdx.x] = 0;
}
// 512 blocks per type (NE/256); block never straddles a type
__global__ __launch_bounds__(256) void k_bcount(const int* __restrict__ edges,
                                                u32* __restrict__ bcnt) {
    __shared__ u32 lcnt[8];
    int t = blockIdx.x >> 9;
    int e = ((blockIdx.x & 511) << 8) + threadIdx.x;
    if (threadIdx.x < 8) lcnt[threadIdx.x] = 0;
    __syncthreads();
    int d = edges[(t * 2 + 1) * NE + e];
    atomicAdd(&lcnt[d >> 11], 1u);
    __syncthreads();
    if (threadIdx.x < 8) atomicAdd(&bcnt[t * 8 + threadIdx.x], lcnt[threadIdx.x]);
}
__global__ __launch_bounds__(64) void k_bscan(const u32* __restrict__ bcnt,
                                              u32* __restrict__ bcur) {
    if (threadIdx.x == 0) {
        for (int t = 0; t < NT; ++t) {
            u32 run = 0;
            for (int b = 0; b < 8; ++b) {
                bcur[t * 8 + b] = run;
                run += bcnt[t * 8 + b];
            }
        }
    }
}
__global__ __launch_bounds__(256) void k_bscatter(const int* __restrict__ edges,
                                                  u32* __restrict__ bcur,
                                                  int* __restrict__ esrc,
                                                  int* __restrict__ edst) {
    __shared__ u32 lcnt[8], lbase[8];
    int t = blockIdx.x >> 9;
    int e = ((blockIdx.x & 511) << 8) + threadIdx.x;
    if (threadIdx.x < 8) lcnt[threadIdx.x] = 0;
    __syncthreads();
    int s = edges[(t * 2) * NE + e];
    int d = edges[(t * 2 + 1) * NE + e];
    int b = d >> 11;
    u32 rank = atomicAdd(&lcnt[b], 1u);
    __syncthreads();
    if (threadIdx.x < 8)
        lbase[threadIdx.x] = atomicAdd(&bcur[t * 8 + threadIdx.x], lcnt[threadIdx.x]);
    __syncthreads();
    u32 slot = lbase[b] + rank;
    esrc[(size_t)t * NE + slot] = s;
    edst[(size_t)t * NE + slot] = d;
}

// ---------------- fp32 GEMM -> bf16 out (Ps0 only; tiny) ----------------
__global__ __launch_bounds__(256) void k_gemm32(const float* __restrict__ A, int lda,
                                                const float* __restrict__ B, int ldb,
                                                u16* __restrict__ C, int ldc, int K) {
    __shared__ float As[64][33];
    __shared__ float Bs[32][64];
    int tid = threadIdx.x;
    int ty = tid >> 4, tx = tid & 15;
    int rbase = blockIdx.x * 64, cbase = blockIdx.y * 64;
    float acc[4][4] = {};
    for (int k0 = 0; k0 < K; k0 += 32) {
        __syncthreads();
#pragma unroll
        for (int i = 0; i < 8; ++i) {
            int id = tid + i * 256;
            int r = id >> 5, c = id & 31;
            As[r][c] = A[(size_t)(rbase + r) * lda + k0 + c];
        }
#pragma unroll
        for (int i = 0; i < 8; ++i) {
            int id = tid + i * 256;
            int r = id >> 6, c = id & 63;
            Bs[r][c] = B[(size_t)(k0 + r) * ldb + cbase + c];
        }
        __syncthreads();
#pragma unroll 8
        for (int kk = 0; kk < 32; ++kk) {
            float a[4], bv[4];
#pragma unroll
            for (int i = 0; i < 4; ++i) a[i] = As[ty * 4 + i][kk];
#pragma unroll
            for (int j = 0; j < 4; ++j) bv[j] = Bs[kk][tx * 4 + j];
#pragma unroll
            for (int i = 0; i < 4; ++i)
#pragma unroll
                for (int j = 0; j < 4; ++j) acc[i][j] = fmaf(a[i], bv[j], acc[i][j]);
        }
    }
#pragma unroll
    for (int i = 0; i < 4; ++i)
#pragma unroll
        for (int j = 0; j < 4; ++j)
            C[(size_t)(rbase + ty * 4 + i) * ldc + cbase + tx * 4 + j] = f2bf(acc[i][j]);
}

// ---------------- W2/W3/W4 -> fragment-packed bf16 hi/lo ----------------
__global__ __launch_bounds__(256) void k_prepw(const float* __restrict__ W2,
                                               const float* __restrict__ W3,
                                               const float* __restrict__ W4,
                                               u16* __restrict__ WF) {
    int bid = blockIdx.x;                  // 240 = 5*3*2*8
    int t = bid / 48;
    int l = (bid / 16) % 3;
    int p = (bid / 8) % 2;
    int nt = bid % 8;
    int tid = threadIdx.x;
    int ks = tid >> 6, lane = tid & 63;
    const float* W = (l == 0 ? W2 : l == 1 ? W3 : W4) + t * 16384;
    int n = nt * 16 + (lane & 15);
    int kb = ks * 32 + (lane >> 4) * 8;
    ushort8 o;
#pragma unroll
    for (int i = 0; i < 8; ++i) {
        float w = W[(size_t)(kb + i) * H + n];
        u16 h = f2bf(w);
        o[i] = (p == 0) ? h : f2bf(w - bf2f(h));
    }
    size_t base = ((size_t)((((t * 3 + l) * 2 + p) * 8 + nt) * 4 + ks) * 64 + lane) * 8;
    *reinterpret_cast<ushort8*>(WF + base) = o;
}

// ---------------- pack [Wih;Whh] -> B-frags hi/lo ----------------
__global__ __launch_bounds__(256) void k_packBw(const float* __restrict__ Wih,
                                                const float* __restrict__ Whh,
                                                u16* __restrict__ Bw, size_t bplane) {
    int nt = blockIdx.x;                           // 32
    int kt = blockIdx.y * 4 + (threadIdx.x >> 6);  // grid.y=7 -> 0..27
    int lane = threadIdx.x & 63;
    int n = nt * 16 + (lane & 15);
    int k0 = kt * 32 + ((lane >> 4) << 3);
    ushort8 hh, ll;
#pragma unroll
    for (int i = 0; i < 8; ++i) {
        int k = k0 + i;
        float wv = (k < 768) ? Wih[(size_t)k * G4 + n] : Whh[(size_t)(k - 768) * G4 + n];
        u16 h = f2bf(wv);
        hh[i] = h;
        ll[i] = f2bf(wv - bf2f(h));
    }
    size_t fo = ((size_t)(nt * AKT + kt) * 64 + lane) * 8;
    *reinterpret_cast<ushort8*>(Bw + fo) = hh;
    *reinterpret_cast<ushort8*>(Bw + bplane + fo) = ll;
}

// ---------------- pack projection weights (from W1) -> B-frags hi/lo ----------------
__global__ __launch_bounds__(256) void k_packBp(const float* __restrict__ W1,
                                                u16* __restrict__ Bp, size_t bplane) {
    int nt = blockIdx.x;               // 72
    int kt = threadIdx.x >> 6;         // 0..3
    int lane = threadIdx.x & 63;
    int n = nt * 16 + (lane & 15);
    int k0 = kt * 32 + ((lane >> 4) << 3);
    int t, roff, j;
    if (n < 640) { t = n >> 7; j = n & 127; roff = 128; }
    else { int m = n - 640; t = (m >> 7) + 1; j = m & 127; roff = 0; }
    ushort8 hh, ll;
#pragma unroll
    for (int i = 0; i < 8; ++i) {
        float wv = W1[((size_t)t * 256 + roff + k0 + i) * H + j];
        u16 h = f2bf(wv);
        hh[i] = h;
        ll[i] = f2bf(wv - bf2f(h));
    }
    size_t fo = ((size_t)(nt * 4 + kt) * 64 + lane) * 8;
    *reinterpret_cast<ushort8*>(Bp + fo) = hh;
    *reinterpret_cast<ushort8*>(Bp + bplane + fo) = ll;
}

// ---------------- MFMA GEMM, 2-term (Ah*Bh + Ah*Bl); A from Ap frags, or msg fp16 for kt 4:24 ----------------
// psplit=1: bf16 out in per-type layout P9[col>>7][row][col&127]
__global__ __launch_bounds__(256) void k_gemm_bf(const u16* __restrict__ Ap,
                                                 int aktbase,
                                                 const __half* __restrict__ msgA,
                                                 const u16* __restrict__ Bp, size_t bplane,
                                                 int bKT, int nkt,
                                                 float* __restrict__ Cf, u16* __restrict__ Ch,
                                                 int ldc, int psplit) {
    int tid = threadIdx.x;
    int w = tid >> 6, lane = tid & 63;
    int wr = w >> 1, wc = w & 1;
    int mtb = blockIdx.x * 8 + wr * 4;
    int ntb = blockIdx.y * 8 + wc * 4;
    f32x4 acc[4][4] = {};
    for (int kk = 0; kk < nkt; ++kk) {
        short8 Ah[4], Bh[4], Bl[4];
        if (msgA && kk >= 4 && kk < 24) {
            int k0 = (kk - 4) * 32 + ((lane >> 4) << 3);
            int tt = k0 >> 7, fl0 = k0 & 127;
            int bit = (fl0 >> 4) & 1;
            int wbase = tt * 128 + ((fl0 >> 5) << 5) + ((fl0 & 15) << 1);
#pragma unroll
            for (int m = 0; m < 4; ++m) {
                int row = (mtb + m) * 16 + (lane & 15);
                const uint4v* dwp = reinterpret_cast<const uint4v*>(msgA + (size_t)row * MSGW + wbase);
                uint4v q0 = dwp[0], q1 = dwp[1];
                u32 dws[8] = {q0[0], q0[1], q0[2], q0[3], q1[0], q1[1], q1[2], q1[3]};
                short8 hv;
#pragma unroll
                for (int i = 0; i < 8; ++i) {
                    u16 raw = bit ? (u16)(dws[i] >> 16) : (u16)(dws[i] & 0xffffu);
                    hv[i] = (short)f2bf(h2f(raw));
                }
                Ah[m] = hv;
            }
        } else {
#pragma unroll
            for (int m = 0; m < 4; ++m) {
                size_t fo = ((size_t)((mtb + m) * AKT + aktbase + kk) * 64 + lane) * 8;
                Ah[m] = *reinterpret_cast<const short8*>(Ap + fo);
            }
        }
#pragma unroll
        for (int n = 0; n < 4; ++n) {
            size_t fo = ((size_t)((ntb + n) * bKT + kk) * 64 + lane) * 8;
            Bh[n] = *reinterpret_cast<const short8*>(Bp + fo);
            Bl[n] = *reinterpret_cast<const short8*>(Bp + bplane + fo);
        }
#pragma unroll
        for (int m = 0; m < 4; ++m)
#pragma unroll
            for (int n = 0; n < 4; ++n) {
                acc[m][n] = __builtin_amdgcn_mfma_f32_16x16x32_bf16(Ah[m], Bh[n], acc[m][n], 0, 0, 0);
                acc[m][n] = __builtin_amdgcn_mfma_f32_16x16x32_bf16(Ah[m], Bl[n], acc[m][n], 0, 0, 0);
            }
    }
#pragma unroll
    for (int m = 0; m < 4; ++m)
#pragma unroll
        for (int r = 0; r < 4; ++r) {
            int row = (mtb + m) * 16 + (lane >> 4) * 4 + r;
#pragma unroll
            for (int n = 0; n < 4; ++n) {
                int col = (ntb + n) * 16 + (lane & 15);
                float v = acc[m][n][r];
                if (Ch) {
                    if (psplit)
                        Ch[((size_t)(col >> 7) * NCELL + row) * H + (col & 127)] = f2bf(v);
                    else
                        Ch[(size_t)row * ldc + col] = f2bf(v);
                } else {
                    Cf[(size_t)row * ldc + col] = v;
                }
            }
        }
}

// ---------------- fused per-edge MLP; bucketed edges + XCD-affine chunks ----------------
__global__ __launch_bounds__(256, 4) void k_edge(const int* __restrict__ esrc,
                                                 const int* __restrict__ edst,
                                                 const u16* __restrict__ P,   // P9 layout
                                                 const u16* __restrict__ Ps0,
                                                 const u16* __restrict__ WF,
                                                 const float* __restrict__ bb1,
                                                 const float* __restrict__ bb2,
                                                 const float* __restrict__ bb3,
                                                 const float* __restrict__ bb4,
                                                 __half* __restrict__ msg) {
    __shared__ u16 zh[EB * H];    // 32KB, 16B-chunk XOR swizzle
    __shared__ int sdst[EB];
    int tid = threadIdx.x;
    int w = tid >> 6, lane = tid & 63;
    int bid = blockIdx.x;
    int t = bid >> 10;
    int p = bid & 1023;
    int tile = ((p & 7) << 7) | (p >> 3);   // bucket-major chunk -> XCD-affine
    int ebase = tile * EB;

    // ---- layer 1 (per-type P9 gathers; contiguous bucketed edge arrays) ----
    {
        int row = tid >> 1, half = tid & 1;
        size_t e = (size_t)t * NE + ebase + row;
        int sn = esrc[e];
        int dn = edst[e];
        if (half == 0) sdst[row] = dn;
        const u16* ps = (t == 0) ? Ps0 + (size_t)sn * H
                                 : P + ((size_t)(t + 4) * NCELL + sn) * H;
        const u16* pd = P + ((size_t)t * NCELL + dn) * H;
        const float* bb = bb1 + t * H;
#pragma unroll
        for (int cc = 0; cc < 8; ++cc) {
            int c8 = half * 8 + cc;
            ushort8 a = *reinterpret_cast<const ushort8*>(ps + c8 * 8);
            ushort8 d = *reinterpret_cast<const ushort8*>(pd + c8 * 8);
            float4 b0 = *reinterpret_cast<const float4*>(bb + c8 * 8);
            float4 b1v = *reinterpret_cast<const float4*>(bb + c8 * 8 + 4);
            float bv[8] = {b0.x, b0.y, b0.z, b0.w, b1v.x, b1v.y, b1v.z, b1v.w};
            ushort8 hh;
#pragma unroll
            for (int i = 0; i < 8; ++i)
                hh[i] = f2bf(fmaxf(bf2f(a[i]) + bf2f(d[i]) + bv[i], 0.f));
            *reinterpret_cast<ushort8*>(&zh[row * H + ((c8 ^ (row & 7)) << 3)]) = hh;
        }
    }
    __syncthreads();

    const u16* wfbase = WF + (size_t)(t * 3) * 32768;
    short8 Bh[2][4], Bl[2][4];

    // ---- layers 2,3: transposed compute mfma(W,z) -> packed b64 writeback ----
#pragma unroll 1
    for (int l = 0; l < 2; ++l) {
        const u16* wl = wfbase + l * 32768;
#pragma unroll
        for (int fg = 0; fg < 2; ++fg)
#pragma unroll
            for (int ks = 0; ks < 4; ++ks) {
                int nt = 2 * w + fg;
                Bh[fg][ks] = *reinterpret_cast<const short8*>(wl + ((nt * 4 + ks) * 64 + lane) * 8);
                Bl[fg][ks] = *reinterpret_cast<const short8*>(wl + ((32 + nt * 4 + ks) * 64 + lane) * 8);
            }
        f32x4 acc[8][2];
#pragma unroll
        for (int et = 0; et < 8; ++et)
#pragma unroll
            for (int fg = 0; fg < 2; ++fg)
                acc[et][fg] = (f32x4){0.f, 0.f, 0.f, 0.f};
#pragma unroll
        for (int et = 0; et < 8; ++et) {
            short8 Zf[4];
            int rr = et * 16 + (lane & 15);
#pragma unroll
            for (int ks = 0; ks < 4; ++ks) {
                int ch = ks * 4 + (lane >> 4);
                Zf[ks] = *reinterpret_cast<const short8*>(&zh[rr * H + ((ch ^ (rr & 7)) << 3)]);
            }
#pragma unroll
            for (int fg = 0; fg < 2; ++fg)
#pragma unroll
                for (int ks = 0; ks < 4; ++ks) {
                    acc[et][fg] = __builtin_amdgcn_mfma_f32_16x16x32_bf16(Bh[fg][ks], Zf[ks], acc[et][fg], 0, 0, 0);
                    acc[et][fg] = __builtin_amdgcn_mfma_f32_16x16x32_bf16(Bl[fg][ks], Zf[ks], acc[et][fg], 0, 0, 0);
                }
        }
        __syncthreads();   // all reads of zh done
        const float* bb = (l == 0 ? bb2 : bb3) + t * H;
        float bi[2][4];
#pragma unroll
        for (int fg = 0; fg < 2; ++fg)
#pragma unroll
            for (int r = 0; r < 4; ++r)
                bi[fg][r] = bb[(2 * w + fg) * 16 + (lane >> 4) * 4 + r];
#pragma unroll
        for (int et = 0; et < 8; ++et) {
            int e = et * 16 + (lane & 15);
#pragma unroll
            for (int fg = 0; fg < 2; ++fg) {
                int f0 = (2 * w + fg) * 16 + (lane >> 4) * 4;
                ushort4v v;
#pragma unroll
                for (int r = 0; r < 4; ++r)
                    v[r] = f2bf(fmaxf(acc[et][fg][r] + bi[fg][r], 0.f));
                int off = e * H + (((f0 >> 3) ^ (e & 7)) << 3) + (f0 & 7);
                *reinterpret_cast<ushort4v*>(&zh[off]) = v;
            }
        }
        __syncthreads();   // writes visible
    }

    // ---- layer 4: normal orientation, per-mt MFMA + packed-fp16 atomic scatter ----
    {
        const u16* wl = wfbase + 2 * 32768;
#pragma unroll
        for (int ng = 0; ng < 2; ++ng)
#pragma unroll
            for (int ks = 0; ks < 4; ++ks) {
                int nt = 2 * w + ng;
                Bh[ng][ks] = *reinterpret_cast<const short8*>(wl + ((nt * 4 + ks) * 64 + lane) * 8);
                Bl[ng][ks] = *reinterpret_cast<const short8*>(wl + ((32 + nt * 4 + ks) * 64 + lane) * 8);
            }
        const float* bb = bb4 + t * H;
        float bi[2];
#pragma unroll
        for (int ng = 0; ng < 2; ++ng) bi[ng] = bb[(2 * w + ng) * 16 + (lane & 15)];
        int pos = (w * 16 + (lane & 15)) * 2;   // even -> 4B-aligned __half2
#pragma unroll 1
        for (int mt = 0; mt < 8; ++mt) {
            short8 Ah[4];
            int rr = mt * 16 + (lane & 15);
#pragma unroll
            for (int ks = 0; ks < 4; ++ks) {
                int ch = ks * 4 + (lane >> 4);
                Ah[ks] = *reinterpret_cast<const short8*>(&zh[rr * H + ((ch ^ (rr & 7)) << 3)]);
            }
            f32x4 a0 = (f32x4){0.f, 0.f, 0.f, 0.f};
            f32x4 a1 = (f32x4){0.f, 0.f, 0.f, 0.f};
#pragma unroll
            for (int ks = 0; ks < 4; ++ks) {
                a0 = __builtin_amdgcn_mfma_f32_16x16x32_bf16(Ah[ks], Bh[0][ks], a0, 0, 0, 0);
                a0 = __builtin_amdgcn_mfma_f32_16x16x32_bf16(Ah[ks], Bl[0][ks], a0, 0, 0, 0);
                a1 = __builtin_amdgcn_mfma_f32_16x16x32_bf16(Ah[ks], Bh[1][ks], a1, 0, 0, 0);
                a1 = __builtin_amdgcn_mfma_f32_16x16x32_bf16(Ah[ks], Bl[1][ks], a1, 0, 0, 0);
            }
#pragma unroll
            for (int r = 0; r < 4; ++r) {
                int d = sdst[mt * 16 + (lane >> 4) * 4 + r];
                __half2* mp = reinterpret_cast<__half2*>(msg + (size_t)d * MSGW + t * H + pos);
                unsafeAtomicAdd(mp, __floats2half2_rn(a0[r] + bi[0], a1[r] + bi[1]));
            }
        }
    }
}

// ---------------- LSTM pointwise + h frag pack (kt 24:28, hi only) + fused logits ----------------
__global__ __launch_bounds__(256) void k_lstm(const float* __restrict__ gates,
                                              float* __restrict__ cst,
                                              u16* __restrict__ Ap,
                                              const float* __restrict__ oemb,
                                              float* __restrict__ out) {
    __shared__ float sh[16][132];
    __shared__ float oe[17][132];
    int mtile = blockIdx.x, tid = threadIdx.x;
    int b = mtile >> 4;   // 16 mtiles per batch
    for (int id = tid; id < 17 * 128; id += 256) {
        int r = id >> 7, c = id & 127;
        oe[r][c] = oemb[(b * 17 + r) * H + c];
    }
#pragma unroll
    for (int e = 0; e < 8; ++e) {
        int idx = e * 256 + tid;
        int row = idx >> 7, c = idx & 127;
        int grow = mtile * 16 + row;
        const float* g = gates + (size_t)grow * G4;
        float ig = g[c], fg = g[128 + c], gg = g[256 + c], og = g[384 + c];
        size_t ci = (size_t)grow * H + c;
        float c_old = cst[ci];
        float i_s = 1.f / (1.f + expf(-ig));
        float f_s = 1.f / (1.f + expf(-fg));
        float o_s = 1.f / (1.f + expf(-og));
        float c_new = f_s * c_old + i_s * tanhf(gg);
        float h_new = o_s * tanhf(c_new);
        cst[ci] = c_new;
        sh[row][c] = h_new;
    }
    __syncthreads();
    // h frag pack (hi only)
    {
        int kt = tid >> 6, lane = tid & 63;
        int row = lane & 15, c0 = kt * 32 + ((lane >> 4) << 3);
        ushort8 hh;
#pragma unroll
        for (int i = 0; i < 8; ++i) hh[i] = f2bf(sh[row][c0 + i]);
        size_t fo = ((size_t)(mtile * AKT + 24 + kt) * 64 + lane) * 8;
        *reinterpret_cast<ushort8*>(Ap + fo) = hh;
    }
    // logits
    {
        int row = tid & 15, cls = tid >> 4;
        const float4* hv = reinterpret_cast<const float4*>(&sh[row][0]);
        const float4* ov = reinterpret_cast<const float4*>(&oe[cls][0]);
        float a = 0.f;
#pragma unroll
        for (int v = 0; v < 32; ++v) {
            float4 h4 = hv[v], o4 = ov[v];
            a = fmaf(h4.x, o4.x, fmaf(h4.y, o4.y, fmaf(h4.z, o4.z, fmaf(h4.w, o4.w, a))));
        }
        out[(size_t)(mtile * 16 + row) * 17 + cls] = a;
        if (tid < 16) {
            const float4* hv2 = reinterpret_cast<const float4*>(&sh[tid][0]);
            const float4* ov2 = reinterpret_cast<const float4*>(&oe[16][0]);
            float a2 = 0.f;
#pragma unroll
            for (int v = 0; v < 32; ++v) {
                float4 h4 = hv2[v], o4 = ov2[v];
                a2 = fmaf(h4.x, o4.x, fmaf(h4.y, o4.y, fmaf(h4.z, o4.z, fmaf(h4.w, o4.w, a2))));
            }
            out[(size_t)(mtile * 16 + tid) * 17 + 16] = a2;
        }
    }
}

extern "C" void kernel_launch(void* const* d_in, const int* in_sizes, int n_in,
                              void* d_out, int out_size, void* d_ws, size_t ws_size,
                              hipStream_t stream) {
    (void)in_sizes; (void)n_in; (void)out_size; (void)ws_size;
    const int*   edges = (const int*)d_in[0];
    const int*   q     = (const int*)d_in[1];
    const float* emb   = (const float*)d_in[2];
    const float* oemb  = (const float*)d_in[3];
    const float* W1    = (const float*)d_in[4];
    const float* b1    = (const float*)d_in[5];
    const float* W2    = (const float*)d_in[6];
    const float* b2    = (const float*)d_in[7];
    const float* W3    = (const float*)d_in[8];
    const float* b3    = (const float*)d_in[9];
    const float* W4    = (const float*)d_in[10];
    const float* b4    = (const float*)d_in[11];
    const float* Wih   = (const float*)d_in[12];
    const float* Whh   = (const float*)d_in[13];
    float* out = (float*)d_out;

    // ---- workspace layout (bytes, 256-aligned) ----
    char* wsp = (char*)d_ws;
    size_t off = 0;
    auto alloc = [&](size_t bytes) { void* p = wsp + off; off = (off + bytes + 255) & ~(size_t)255; return p; };
    __half* msg   = (__half*)alloc((size_t)NCELL * MSGW * 2);       // 21MB fp16
    u16*   P      = (u16*)  alloc((size_t)9 * NCELL * H * 2);       // 37.7MB (P9 layout)
    float* gates  = (float*)P;                                      // alias
    float* cst    = (float*)alloc((size_t)NCELL * H * 4);
    u16*   Ps0    = (u16*)  alloc((size_t)NCLU * H * 2);
    float* avg    = (float*)alloc((size_t)64 * H * 4);
    size_t aplane = (size_t)NCELL * 896;
    u16*   Ap     = (u16*)  alloc(aplane * 2);                      // hi plane only
    u16*   WF     = (u16*)  alloc((size_t)983040 * 2);
    size_t bwpl   = (size_t)512 * 896;
    u16*   Bw     = (u16*)  alloc(bwpl * 2 * 2);
    size_t bppl   = (size_t)1152 * 128;
    u16*   Bp     = (u16*)  alloc(bppl * 2 * 2);
    int*   esrc   = (int*)  alloc((size_t)NT * NE * 4);
    int*   edst   = (int*)  alloc((size_t)NT * NE * 4);
    u32*   bcnt   = (u32*)  alloc(64 * 4);
    u32*   bcur   = (u32*)  alloc(64 * 4);

    // ---- one-time prep ----
    k_avg<<<64, 128, 0, stream>>>(emb, avg);
    k_init<<<1024, 256, 0, stream>>>(q, emb, avg, Ap, cst);
    k_prepw<<<240, 256, 0, stream>>>(W2, W3, W4, WF);
    {
        dim3 g(32, 7);
        k_packBw<<<g, 256, 0, stream>>>(Wih, Whh, Bw, bwpl);
    }
    k_packBp<<<72, 256, 0, stream>>>(W1, Bp, bppl);
    {
        dim3 g0(17, 2);
        k_gemm32<<<g0, 256, 0, stream>>>(emb, H, W1, H, Ps0, H, H);
    }
    // dst-bucket counting sort (8 buckets per type), LDS-aggregated
    k_bzero<<<1, 64, 0, stream>>>(bcnt);
    k_bcount<<<NT * NE / 256, 256, 0, stream>>>(edges, bcnt);
    k_bscan<<<1, 64, 0, stream>>>(bcnt, bcur);
    k_bscatter<<<NT * NE / 256, 256, 0, stream>>>(edges, bcur, esrc, edst);

    for (int s = 0; s < SSTEPS; ++s) {
        k_zeromsg<<<NCELL * MSGW / 8 / 256, 256, 0, stream>>>(msg);
        // P9 = h @ Wproj (bf16, per-type layout); A-frags kt 0:4 (cell_x) at s=0 else 24:28 (h)
        {
            dim3 g(128, 9);
            k_gemm_bf<<<g, 256, 0, stream>>>(Ap, (s == 0) ? 0 : 24, nullptr,
                                             Bp, bppl, 4, 4, nullptr, P, H, 1);
        }
        k_edge<<<NT * (NE / EB), 256, 0, stream>>>(esrc, edst, P, Ps0, WF,
                                                   b1, b2, b3, b4, msg);
        // gates = [cell_x, msg, h] @ [Wih; Whh]  (K = 768 at s=0, 896 else); msg read in-place
        {
            dim3 g(128, 4);
            k_gemm_bf<<<g, 256, 0, stream>>>(Ap, 0, msg, Bw, bwpl, AKT,
                                             (s == 0) ? 24 : 28, gates, nullptr, G4, 0);
        }
        k_lstm<<<1024, 256, 0, stream>>>(gates, cst, Ap, oemb,
                                         out + (size_t)s * NCELL * 17);
    }
}

// Round 16
// 985.000 us; speedup vs baseline: 5.0137x; 1.0760x over previous
//
#include <hip/hip_runtime.h>
#include <hip/hip_fp16.h>
#include <hip/hip_bf16.h>
#include <math.h>

#define H 128
#define SSTEPS 3
#define NE 131072
#define NT 5
#define NCELL 16384
#define NCLU 1088
#define G4 512
#define MSGW 640     // 5*H message block (fp16, column-permuted per type)
#define AKT 28       // Apack kt count (896 K-cols / 32)
#define EB 128

typedef unsigned short u16;
typedef unsigned int u32;
typedef __attribute__((ext_vector_type(8))) short short8;
typedef __attribute__((ext_vector_type(8))) unsigned short ushort8;
typedef __attribute__((ext_vector_type(4))) unsigned short ushort4v;
typedef __attribute__((ext_vector_type(4))) float f32x4;
typedef __attribute__((ext_vector_type(4))) unsigned int uint4v;

__device__ __forceinline__ u16 f2bf(float f) {
    __hip_bfloat16 h = __float2bfloat16(f);   // RNE; pairs fuse to v_cvt_pk_bf16_f32
    u16 u;
    __builtin_memcpy(&u, &h, 2);
    return u;
}
__device__ __forceinline__ float bf2f(u16 h) {
    return __uint_as_float(((unsigned int)h) << 16);
}
__device__ __forceinline__ float h2f(u16 r) {
    __half hv;
    __builtin_memcpy(&hv, &r, 2);
    return __half2float(hv);
}

// ---------------- avg of class embeddings 1..16 per batch ----------------
__global__ __launch_bounds__(128) void k_avg(const float* __restrict__ emb,
                                             float* __restrict__ avg) {
    int b = blockIdx.x, hc = threadIdx.x;
    float s = 0.f;
#pragma unroll
    for (int r = 1; r <= 16; ++r) s += emb[(b * 17 + r) * H + hc];
    avg[b * H + hc] = s * (1.0f / 16.0f);
}

// ---------------- init: cell_x -> Apack kt 0:4 (hi only); zero cst ----------------
__global__ __launch_bounds__(256) void k_init(const int* __restrict__ q,
                                              const float* __restrict__ emb,
                                              const float* __restrict__ avg,
                                              u16* __restrict__ Ap,
                                              float* __restrict__ cst) {
    __shared__ float sx[16][132];
    int mtile = blockIdx.x, tid = threadIdx.x;
#pragma unroll
    for (int e = 0; e < 8; ++e) {
        int idx = e * 256 + tid;
        int row = idx >> 7, c = idx & 127;
        int grow = mtile * 16 + row;
        int b = grow >> 8;
        int qi = q[grow];
        const float* src = (qi == 0) ? (avg + b * H) : (emb + (b * 17 + qi) * H);
        float v = src[c];
        sx[row][c] = v;
        cst[(size_t)grow * H + c] = 0.f;
    }
    __syncthreads();
    int kt = tid >> 6, lane = tid & 63;
    int row = lane & 15, c0 = kt * 32 + ((lane >> 4) << 3);
    ushort8 hh;
#pragma unroll
    for (int i = 0; i < 8; ++i) hh[i] = f2bf(sx[row][c0 + i]);
    size_t fo = ((size_t)(mtile * AKT + kt) * 64 + lane) * 8;
    *reinterpret_cast<ushort8*>(Ap + fo) = hh;
}

// ---------------- zero msg buffer (fp16, 21MB) ----------------
__global__ __launch_bounds__(256) void k_zeromsg(__half* __restrict__ msg) {
    int idx = blockIdx.x * 256 + threadIdx.x;
    reinterpret_cast<float4*>(msg)[idx] = make_float4(0.f, 0.f, 0.f, 0.f);
}

// ---------------- fp32 GEMM -> bf16 out (Ps0 only; tiny) ----------------
__global__ __launch_bounds__(256) void k_gemm32(const float* __restrict__ A, int lda,
                                                const float* __restrict__ B, int ldb,
                                                u16* __restrict__ C, int ldc, int K) {
    __shared__ float As[64][33];
    __shared__ float Bs[32][64];
    int tid = threadIdx.x;
    int ty = tid >> 4, tx = tid & 15;
    int rbase = blockIdx.x * 64, cbase = blockIdx.y * 64;
    float acc[4][4] = {};
    for (int k0 = 0; k0 < K; k0 += 32) {
        __syncthreads();
#pragma unroll
        for (int i = 0; i < 8; ++i) {
            int id = tid + i * 256;
            int r = id >> 5, c = id & 31;
            As[r][c] = A[(size_t)(rbase + r) * lda + k0 + c];
        }
#pragma unroll
        for (int i = 0; i < 8; ++i) {
            int id = tid + i * 256;
            int r = id >> 6, c = id & 63;
            Bs[r][c] = B[(size_t)(k0 + r) * ldb + cbase + c];
        }
        __syncthreads();
#pragma unroll 8
        for (int kk = 0; kk < 32; ++kk) {
            float a[4], bv[4];
#pragma unroll
            for (int i = 0; i < 4; ++i) a[i] = As[ty * 4 + i][kk];
#pragma unroll
            for (int j = 0; j < 4; ++j) bv[j] = Bs[kk][tx * 4 + j];
#pragma unroll
            for (int i = 0; i < 4; ++i)
#pragma unroll
                for (int j = 0; j < 4; ++j) acc[i][j] = fmaf(a[i], bv[j], acc[i][j]);
        }
    }
#pragma unroll
    for (int i = 0; i < 4; ++i)
#pragma unroll
        for (int j = 0; j < 4; ++j)
            C[(size_t)(rbase + ty * 4 + i) * ldc + cbase + tx * 4 + j] = f2bf(acc[i][j]);
}

// ---------------- W2/W3/W4 -> fragment-packed bf16 hi/lo ----------------
__global__ __launch_bounds__(256) void k_prepw(const float* __restrict__ W2,
                                               const float* __restrict__ W3,
                                               const float* __restrict__ W4,
                                               u16* __restrict__ WF) {
    int bid = blockIdx.x;                  // 240 = 5*3*2*8
    int t = bid / 48;
    int l = (bid / 16) % 3;
    int p = (bid / 8) % 2;
    int nt = bid % 8;
    int tid = threadIdx.x;
    int ks = tid >> 6, lane = tid & 63;
    const float* W = (l == 0 ? W2 : l == 1 ? W3 : W4) + t * 16384;
    int n = nt * 16 + (lane & 15);
    int kb = ks * 32 + (lane >> 4) * 8;
    ushort8 o;
#pragma unroll
    for (int i = 0; i < 8; ++i) {
        float w = W[(size_t)(kb + i) * H + n];
        u16 h = f2bf(w);
        o[i] = (p == 0) ? h : f2bf(w - bf2f(h));
    }
    size_t base = ((size_t)((((t * 3 + l) * 2 + p) * 8 + nt) * 4 + ks) * 64 + lane) * 8;
    *reinterpret_cast<ushort8*>(WF + base) = o;
}

// ---------------- pack [Wih;Whh] -> B-frags hi/lo ----------------
__global__ __launch_bounds__(256) void k_packBw(const float* __restrict__ Wih,
                                                const float* __restrict__ Whh,
                                                u16* __restrict__ Bw, size_t bplane) {
    int nt = blockIdx.x;                           // 32
    int kt = blockIdx.y * 4 + (threadIdx.x >> 6);  // grid.y=7 -> 0..27
    int lane = threadIdx.x & 63;
    int n = nt * 16 + (lane & 15);
    int k0 = kt * 32 + ((lane >> 4) << 3);
    ushort8 hh, ll;
#pragma unroll
    for (int i = 0; i < 8; ++i) {
        int k = k0 + i;
        float wv = (k < 768) ? Wih[(size_t)k * G4 + n] : Whh[(size_t)(k - 768) * G4 + n];
        u16 h = f2bf(wv);
        hh[i] = h;
        ll[i] = f2bf(wv - bf2f(h));
    }
    size_t fo = ((size_t)(nt * AKT + kt) * 64 + lane) * 8;
    *reinterpret_cast<ushort8*>(Bw + fo) = hh;
    *reinterpret_cast<ushort8*>(Bw + bplane + fo) = ll;
}

// ---------------- pack projection weights (from W1) -> B-frags hi/lo ----------------
__global__ __launch_bounds__(256) void k_packBp(const float* __restrict__ W1,
                                                u16* __restrict__ Bp, size_t bplane) {
    int nt = blockIdx.x;               // 72
    int kt = threadIdx.x >> 6;         // 0..3
    int lane = threadIdx.x & 63;
    int n = nt * 16 + (lane & 15);
    int k0 = kt * 32 + ((lane >> 4) << 3);
    int t, roff, j;
    if (n < 640) { t = n >> 7; j = n & 127; roff = 128; }
    else { int m = n - 640; t = (m >> 7) + 1; j = m & 127; roff = 0; }
    ushort8 hh, ll;
#pragma unroll
    for (int i = 0; i < 8; ++i) {
        float wv = W1[((size_t)t * 256 + roff + k0 + i) * H + j];
        u16 h = f2bf(wv);
        hh[i] = h;
        ll[i] = f2bf(wv - bf2f(h));
    }
    size_t fo = ((size_t)(nt * 4 + kt) * 64 + lane) * 8;
    *reinterpret_cast<ushort8*>(Bp + fo) = hh;
    *reinterpret_cast<ushort8*>(Bp + bplane + fo) = ll;
}

// ---------------- pack msg fp16 (permuted cols) -> Apack kt 4:24 (hi only) ----------------
// permutation within a 128-col type block: f -> (f>>5)*32 + (f&15)*2 + ((f>>4)&1)
// 8 consecutive f (f0 multiple of 8) sit at u16 indices wbase + bit + 2i -> one 32B window
__global__ __launch_bounds__(256) void k_packmsg(const __half* __restrict__ msg,
                                                 u16* __restrict__ Ap) {
    int mtile = blockIdx.x;
    int ktl = blockIdx.y * 4 + (threadIdx.x >> 6);   // 0..19
    int lane = threadIdx.x & 63;
    int row = mtile * 16 + (lane & 15);
    int c0 = ktl * 32 + ((lane >> 4) << 3);
    const __half* mrow = msg + (size_t)row * MSGW;
    int fl0 = c0 & 127, tt = c0 >> 7;
    int bit = (fl0 >> 4) & 1;
    int wbase = tt * 128 + ((fl0 >> 5) << 5) + ((fl0 & 15) << 1);   // even, 16-aligned
    const uint4v* dwp = reinterpret_cast<const uint4v*>(mrow + wbase);
    uint4v q0 = dwp[0], q1 = dwp[1];
    u32 dws[8] = {q0[0], q0[1], q0[2], q0[3], q1[0], q1[1], q1[2], q1[3]};
    ushort8 hh;
#pragma unroll
    for (int i = 0; i < 8; ++i) {
        u16 raw = bit ? (u16)(dws[i] >> 16) : (u16)(dws[i] & 0xffffu);
        hh[i] = f2bf(h2f(raw));
    }
    size_t fo = ((size_t)(mtile * AKT + 4 + ktl) * 64 + lane) * 8;
    *reinterpret_cast<ushort8*>(Ap + fo) = hh;
}

// ---------------- MFMA GEMM, 2-term (Ah*Bh + Ah*Bl), frag inputs, no LDS ----------------
// psplit=1: bf16 out in per-type layout P9[col>>7][row][col&127]
__global__ __launch_bounds__(256) void k_gemm_bf(const u16* __restrict__ Ap,
                                                 int aktbase,
                                                 const u16* __restrict__ Bp, size_t bplane,
                                                 int bKT, int nkt,
                                                 float* __restrict__ Cf, u16* __restrict__ Ch,
                                                 int ldc, int psplit) {
    int tid = threadIdx.x;
    int w = tid >> 6, lane = tid & 63;
    int wr = w >> 1, wc = w & 1;
    int mtb = blockIdx.x * 8 + wr * 4;
    int ntb = blockIdx.y * 8 + wc * 4;
    f32x4 acc[4][4] = {};
    for (int kk = 0; kk < nkt; ++kk) {
        short8 Ah[4], Bh[4], Bl[4];
#pragma unroll
        for (int m = 0; m < 4; ++m) {
            size_t fo = ((size_t)((mtb + m) * AKT + aktbase + kk) * 64 + lane) * 8;
            Ah[m] = *reinterpret_cast<const short8*>(Ap + fo);
        }
#pragma unroll
        for (int n = 0; n < 4; ++n) {
            size_t fo = ((size_t)((ntb + n) * bKT + kk) * 64 + lane) * 8;
            Bh[n] = *reinterpret_cast<const short8*>(Bp + fo);
            Bl[n] = *reinterpret_cast<const short8*>(Bp + bplane + fo);
        }
#pragma unroll
        for (int m = 0; m < 4; ++m)
#pragma unroll
            for (int n = 0; n < 4; ++n) {
                acc[m][n] = __builtin_amdgcn_mfma_f32_16x16x32_bf16(Ah[m], Bh[n], acc[m][n], 0, 0, 0);
                acc[m][n] = __builtin_amdgcn_mfma_f32_16x16x32_bf16(Ah[m], Bl[n], acc[m][n], 0, 0, 0);
            }
    }
#pragma unroll
    for (int m = 0; m < 4; ++m)
#pragma unroll
        for (int r = 0; r < 4; ++r) {
            int row = (mtb + m) * 16 + (lane >> 4) * 4 + r;
#pragma unroll
            for (int n = 0; n < 4; ++n) {
                int col = (ntb + n) * 16 + (lane & 15);
                float v = acc[m][n][r];
                if (Ch) {
                    if (psplit)
                        Ch[((size_t)(col >> 7) * NCELL + row) * H + (col & 127)] = f2bf(v);
                    else
                        Ch[(size_t)row * ldc + col] = f2bf(v);
                } else {
                    Cf[(size_t)row * ldc + col] = v;
                }
            }
        }
}

// ---------------- fused per-edge MLP; transposed L2/L3 writeback; pk-fp16 atomics ----------------
__global__ __launch_bounds__(256, 4) void k_edge(const int* __restrict__ edges,
                                                 const u16* __restrict__ P,   // P9 layout
                                                 const u16* __restrict__ Ps0,
                                                 const u16* __restrict__ WF,
                                                 const float* __restrict__ bb1,
                                                 const float* __restrict__ bb2,
                                                 const float* __restrict__ bb3,
                                                 const float* __restrict__ bb4,
                                                 __half* __restrict__ msg) {
    __shared__ u16 zh[EB * H];    // 32KB, 16B-chunk XOR swizzle
    __shared__ int sdst[EB];
    int tid = threadIdx.x;
    int w = tid >> 6, lane = tid & 63;
    int bid = blockIdx.x;
    int t = bid >> 10, tile = bid & 1023;
    int ebase = tile * EB;

    // ---- layer 1 (per-type P9 gathers) ----
    {
        int row = tid >> 1, half = tid & 1;
        int e = ebase + row;
        int sn = edges[(t * 2) * NE + e];
        int dn = edges[(t * 2 + 1) * NE + e];
        if (half == 0) sdst[row] = dn;
        const u16* ps = (t == 0) ? Ps0 + (size_t)sn * H
                                 : P + ((size_t)(t + 4) * NCELL + sn) * H;
        const u16* pd = P + ((size_t)t * NCELL + dn) * H;
        const float* bb = bb1 + t * H;
#pragma unroll
        for (int cc = 0; cc < 8; ++cc) {
            int c8 = half * 8 + cc;
            ushort8 a = *reinterpret_cast<const ushort8*>(ps + c8 * 8);
            ushort8 d = *reinterpret_cast<const ushort8*>(pd + c8 * 8);
            float4 b0 = *reinterpret_cast<const float4*>(bb + c8 * 8);
            float4 b1v = *reinterpret_cast<const float4*>(bb + c8 * 8 + 4);
            float bv[8] = {b0.x, b0.y, b0.z, b0.w, b1v.x, b1v.y, b1v.z, b1v.w};
            ushort8 hh;
#pragma unroll
            for (int i = 0; i < 8; ++i)
                hh[i] = f2bf(fmaxf(bf2f(a[i]) + bf2f(d[i]) + bv[i], 0.f));
            *reinterpret_cast<ushort8*>(&zh[row * H + ((c8 ^ (row & 7)) << 3)]) = hh;
        }
    }
    __syncthreads();

    const u16* wfbase = WF + (size_t)(t * 3) * 32768;
    short8 Bh[2][4], Bl[2][4];

    // ---- layers 2,3: transposed compute mfma(W,z) -> packed b64 writeback ----
#pragma unroll 1
    for (int l = 0; l < 2; ++l) {
        const u16* wl = wfbase + l * 32768;
#pragma unroll
        for (int fg = 0; fg < 2; ++fg)
#pragma unroll
            for (int ks = 0; ks < 4; ++ks) {
                int nt = 2 * w + fg;
                Bh[fg][ks] = *reinterpret_cast<const short8*>(wl + ((nt * 4 + ks) * 64 + lane) * 8);
                Bl[fg][ks] = *reinterpret_cast<const short8*>(wl + ((32 + nt * 4 + ks) * 64 + lane) * 8);
            }
        f32x4 acc[8][2];
#pragma unroll
        for (int et = 0; et < 8; ++et)
#pragma unroll
            for (int fg = 0; fg < 2; ++fg)
                acc[et][fg] = (f32x4){0.f, 0.f, 0.f, 0.f};
#pragma unroll
        for (int et = 0; et < 8; ++et) {
            short8 Zf[4];
            int rr = et * 16 + (lane & 15);
#pragma unroll
            for (int ks = 0; ks < 4; ++ks) {
                int ch = ks * 4 + (lane >> 4);
                Zf[ks] = *reinterpret_cast<const short8*>(&zh[rr * H + ((ch ^ (rr & 7)) << 3)]);
            }
#pragma unroll
            for (int fg = 0; fg < 2; ++fg)
#pragma unroll
                for (int ks = 0; ks < 4; ++ks) {
                    acc[et][fg] = __builtin_amdgcn_mfma_f32_16x16x32_bf16(Bh[fg][ks], Zf[ks], acc[et][fg], 0, 0, 0);
                    acc[et][fg] = __builtin_amdgcn_mfma_f32_16x16x32_bf16(Bl[fg][ks], Zf[ks], acc[et][fg], 0, 0, 0);
                }
        }
        __syncthreads();   // all reads of zh done
        const float* bb = (l == 0 ? bb2 : bb3) + t * H;
        float bi[2][4];
#pragma unroll
        for (int fg = 0; fg < 2; ++fg)
#pragma unroll
            for (int r = 0; r < 4; ++r)
                bi[fg][r] = bb[(2 * w + fg) * 16 + (lane >> 4) * 4 + r];
#pragma unroll
        for (int et = 0; et < 8; ++et) {
            int e = et * 16 + (lane & 15);
#pragma unroll
            for (int fg = 0; fg < 2; ++fg) {
                int f0 = (2 * w + fg) * 16 + (lane >> 4) * 4;
                ushort4v v;
#pragma unroll
                for (int r = 0; r < 4; ++r)
                    v[r] = f2bf(fmaxf(acc[et][fg][r] + bi[fg][r], 0.f));
                int off = e * H + (((f0 >> 3) ^ (e & 7)) << 3) + (f0 & 7);
                *reinterpret_cast<ushort4v*>(&zh[off]) = v;
            }
        }
        __syncthreads();   // writes visible
    }

    // ---- layer 4: normal orientation, per-mt MFMA + packed-fp16 atomic scatter ----
    {
        const u16* wl = wfbase + 2 * 32768;
#pragma unroll
        for (int ng = 0; ng < 2; ++ng)
#pragma unroll
            for (int ks = 0; ks < 4; ++ks) {
                int nt = 2 * w + ng;
                Bh[ng][ks] = *reinterpret_cast<const short8*>(wl + ((nt * 4 + ks) * 64 + lane) * 8);
                Bl[ng][ks] = *reinterpret_cast<const short8*>(wl + ((32 + nt * 4 + ks) * 64 + lane) * 8);
            }
        const float* bb = bb4 + t * H;
        float bi[2];
#pragma unroll
        for (int ng = 0; ng < 2; ++ng) bi[ng] = bb[(2 * w + ng) * 16 + (lane & 15)];
        // permuted column pair base: features (2w)*16+c and (2w+1)*16+c
        int pos = (w * 16 + (lane & 15)) * 2;   // even -> 4B-aligned __half2
#pragma unroll 1
        for (int mt = 0; mt < 8; ++mt) {
            short8 Ah[4];
            int rr = mt * 16 + (lane & 15);
#pragma unroll
            for (int ks = 0; ks < 4; ++ks) {
                int ch = ks * 4 + (lane >> 4);
                Ah[ks] = *reinterpret_cast<const short8*>(&zh[rr * H + ((ch ^ (rr & 7)) << 3)]);
            }
            f32x4 a0 = (f32x4){0.f, 0.f, 0.f, 0.f};
            f32x4 a1 = (f32x4){0.f, 0.f, 0.f, 0.f};
#pragma unroll
            for (int ks = 0; ks < 4; ++ks) {
                a0 = __builtin_amdgcn_mfma_f32_16x16x32_bf16(Ah[ks], Bh[0][ks], a0, 0, 0, 0);
                a0 = __builtin_amdgcn_mfma_f32_16x16x32_bf16(Ah[ks], Bl[0][ks], a0, 0, 0, 0);
                a1 = __builtin_amdgcn_mfma_f32_16x16x32_bf16(Ah[ks], Bh[1][ks], a1, 0, 0, 0);
                a1 = __builtin_amdgcn_mfma_f32_16x16x32_bf16(Ah[ks], Bl[1][ks], a1, 0, 0, 0);
            }
#pragma unroll
            for (int r = 0; r < 4; ++r) {
                int d = sdst[mt * 16 + (lane >> 4) * 4 + r];
                __half2* mp = reinterpret_cast<__half2*>(msg + (size_t)d * MSGW + t * H + pos);
                unsafeAtomicAdd(mp, __floats2half2_rn(a0[r] + bi[0], a1[r] + bi[1]));
            }
        }
    }
}

// ---------------- LSTM pointwise + h frag pack (kt 24:28, hi only) + fused logits ----------------
__global__ __launch_bounds__(256) void k_lstm(const float* __restrict__ gates,
                                              float* __restrict__ cst,
                                              u16* __restrict__ Ap,
                                              const float* __restrict__ oemb,
                                              float* __restrict__ out) {
    __shared__ float sh[16][132];
    __shared__ float oe[17][132];
    int mtile = blockIdx.x, tid = threadIdx.x;
    int b = mtile >> 4;   // 16 mtiles per batch
    for (int id = tid; id < 17 * 128; id += 256) {
        int r = id >> 7, c = id & 127;
        oe[r][c] = oemb[(b * 17 + r) * H + c];
    }
#pragma unroll
    for (int e = 0; e < 8; ++e) {
        int idx = e * 256 + tid;
        int row = idx >> 7, c = idx & 127;
        int grow = mtile * 16 + row;
        const float* g = gates + (size_t)grow * G4;
        float ig = g[c], fg = g[128 + c], gg = g[256 + c], og = g[384 + c];
        size_t ci = (size_t)grow * H + c;
        float c_old = cst[ci];
        float i_s = 1.f / (1.f + expf(-ig));
        float f_s = 1.f / (1.f + expf(-fg));
        float o_s = 1.f / (1.f + expf(-og));
        float c_new = f_s * c_old + i_s * tanhf(gg);
        float h_new = o_s * tanhf(c_new);
        cst[ci] = c_new;
        sh[row][c] = h_new;
    }
    __syncthreads();
    // h frag pack (hi only)
    {
        int kt = tid >> 6, lane = tid & 63;
        int row = lane & 15, c0 = kt * 32 + ((lane >> 4) << 3);
        ushort8 hh;
#pragma unroll
        for (int i = 0; i < 8; ++i) hh[i] = f2bf(sh[row][c0 + i]);
        size_t fo = ((size_t)(mtile * AKT + 24 + kt) * 64 + lane) * 8;
        *reinterpret_cast<ushort8*>(Ap + fo) = hh;
    }
    // logits: row = tid&15, cls = tid>>4 (0..15); cls 16 by threads 0..15
    {
        int row = tid & 15, cls = tid >> 4;
        const float4* hv = reinterpret_cast<const float4*>(&sh[row][0]);
        const float4* ov = reinterpret_cast<const float4*>(&oe[cls][0]);
        float a = 0.f;
#pragma unroll
        for (int v = 0; v < 32; ++v) {
            float4 h4 = hv[v], o4 = ov[v];
            a = fmaf(h4.x, o4.x, fmaf(h4.y, o4.y, fmaf(h4.z, o4.z, fmaf(h4.w, o4.w, a))));
        }
        out[(size_t)(mtile * 16 + row) * 17 + cls] = a;
        if (tid < 16) {
            const float4* hv2 = reinterpret_cast<const float4*>(&sh[tid][0]);
            const float4* ov2 = reinterpret_cast<const float4*>(&oe[16][0]);
            float a2 = 0.f;
#pragma unroll
            for (int v = 0; v < 32; ++v) {
                float4 h4 = hv2[v], o4 = ov2[v];
                a2 = fmaf(h4.x, o4.x, fmaf(h4.y, o4.y, fmaf(h4.z, o4.z, fmaf(h4.w, o4.w, a2))));
            }
            out[(size_t)(mtile * 16 + tid) * 17 + 16] = a2;
        }
    }
}

extern "C" void kernel_launch(void* const* d_in, const int* in_sizes, int n_in,
                              void* d_out, int out_size, void* d_ws, size_t ws_size,
                              hipStream_t stream) {
    (void)in_sizes; (void)n_in; (void)out_size; (void)ws_size;
    const int*   edges = (const int*)d_in[0];
    const int*   q     = (const int*)d_in[1];
    const float* emb   = (const float*)d_in[2];
    const float* oemb  = (const float*)d_in[3];
    const float* W1    = (const float*)d_in[4];
    const float* b1    = (const float*)d_in[5];
    const float* W2    = (const float*)d_in[6];
    const float* b2    = (const float*)d_in[7];
    const float* W3    = (const float*)d_in[8];
    const float* b3    = (const float*)d_in[9];
    const float* W4    = (const float*)d_in[10];
    const float* b4    = (const float*)d_in[11];
    const float* Wih   = (const float*)d_in[12];
    const float* Whh   = (const float*)d_in[13];
    float* out = (float*)d_out;

    // ---- workspace layout (bytes, 256-aligned) ----
    char* wsp = (char*)d_ws;
    size_t off = 0;
    auto alloc = [&](size_t bytes) { void* p = wsp + off; off = (off + bytes + 255) & ~(size_t)255; return p; };
    __half* msg   = (__half*)alloc((size_t)NCELL * MSGW * 2);       // 21MB fp16
    u16*   P      = (u16*)  alloc((size_t)9 * NCELL * H * 2);       // 37.7MB (P9 layout)
    float* gates  = (float*)P;                                      // alias
    float* cst    = (float*)alloc((size_t)NCELL * H * 4);
    u16*   Ps0    = (u16*)  alloc((size_t)NCLU * H * 2);
    float* avg    = (float*)alloc((size_t)64 * H * 4);
    size_t aplane = (size_t)NCELL * 896;
    u16*   Ap     = (u16*)  alloc(aplane * 2);                      // hi plane only
    u16*   WF     = (u16*)  alloc((size_t)983040 * 2);
    size_t bwpl   = (size_t)512 * 896;
    u16*   Bw     = (u16*)  alloc(bwpl * 2 * 2);
    size_t bppl   = (size_t)1152 * 128;
    u16*   Bp     = (u16*)  alloc(bppl * 2 * 2);

    // ---- one-time prep ----
    k_avg<<<64, 128, 0, stream>>>(emb, avg);
    k_init<<<1024, 256, 0, stream>>>(q, emb, avg, Ap, cst);
    k_prepw<<<240, 256, 0, stream>>>(W2, W3, W4, WF);
    {
        dim3 g(32, 7);
        k_packBw<<<g, 256, 0, stream>>>(Wih, Whh, Bw, bwpl);
    }
    k_packBp<<<72, 256, 0, stream>>>(W1, Bp, bppl);
    {
        dim3 g0(17, 2);
        k_gemm32<<<g0, 256, 0, stream>>>(emb, H, W1, H, Ps0, H, H);
    }

    for (int s = 0; s < SSTEPS; ++s) {
        k_zeromsg<<<NCELL * MSGW / 8 / 256, 256, 0, stream>>>(msg);
        // P9 = h @ Wproj (bf16, per-type layout); A-frags kt 0:4 (cell_x) at s=0 else 24:28 (h)
        {
            dim3 g(128, 9);
            k_gemm_bf<<<g, 256, 0, stream>>>(Ap, (s == 0) ? 0 : 24,
                                             Bp, bppl, 4, 4, nullptr, P, H, 1);
        }
        k_edge<<<NT * (NE / EB), 256, 0, stream>>>(edges, P, Ps0, WF,
                                                   b1, b2, b3, b4, msg);
        {
            dim3 g(1024, 5);
            k_packmsg<<<g, 256, 0, stream>>>(msg, Ap);
        }
        // gates = [cell_x, msg, h] @ [Wih; Whh]  (K = 768 at s=0, 896 else)
        {
            dim3 g(128, 4);
            k_gemm_bf<<<g, 256, 0, stream>>>(Ap, 0, Bw, bwpl, AKT,
                                             (s == 0) ? 24 : 28, gates, nullptr, G4, 0);
        }
        k_lstm<<<1024, 256, 0, stream>>>(gates, cst, Ap, oemb,
                                         out + (size_t)s * NCELL * 17);
    }
}